// Round 1
// baseline (483.944 us; speedup 1.0000x reference)
//
#include <hip/hip_runtime.h>
#include <hip/hip_bf16.h>
#include <math.h>

// MOE: out[b,o] = sum_n gelu(x@gw^T+gb)[b,n] * (x @ W_n^T)[b,o]
// B=4096, N=32, IDIM=ODIM=1024.
// Strategy: bf16 MFMA GEMM (M=4096, N=1024, K=32*1024) with per-expert
// accumulator fold by g[b,n]; split-K x4 via fp32 atomicAdd into zeroed out.

#define BSZ  4096
#define NEXP 32
#define IDIM 1024
#define ODIM 1024

typedef __attribute__((ext_vector_type(8))) short bf16x8;
typedef __attribute__((ext_vector_type(4))) float f32x4;

#define GLOAD_LDS16(g, l) __builtin_amdgcn_global_load_lds( \
    (const __attribute__((address_space(1))) void*)(g),     \
    (__attribute__((address_space(3))) void*)(l), 16, 0, 0)

__device__ __forceinline__ unsigned short f2bf(float f) {
  unsigned u = __float_as_uint(f);
  unsigned r = (u + 0x7FFFu + ((u >> 16) & 1u)) >> 16;  // RNE
  return (unsigned short)r;
}

// ---------------- zero d_out ----------------
__global__ void zero_kernel(float* __restrict__ out) {
  int i = blockIdx.x * blockDim.x + threadIdx.x;  // one float4 each
  ((float4*)out)[i] = make_float4(0.f, 0.f, 0.f, 0.f);
}

// ---------------- fp32 -> bf16 conversion (8 elems/thread) ----------------
__global__ void conv_kernel(const float* __restrict__ in, unsigned short* __restrict__ outb) {
  int i = blockIdx.x * blockDim.x + threadIdx.x;
  const float4* p = (const float4*)in + (size_t)i * 2;
  float4 a = p[0], b = p[1];
  union { bf16x8 v; unsigned short s[8]; } o;
  o.s[0] = f2bf(a.x); o.s[1] = f2bf(a.y); o.s[2] = f2bf(a.z); o.s[3] = f2bf(a.w);
  o.s[4] = f2bf(b.x); o.s[5] = f2bf(b.y); o.s[6] = f2bf(b.z); o.s[7] = f2bf(b.w);
  ((bf16x8*)outb)[i] = o.v;
}

// ---------------- gate: gT[n][b] = gelu(x[b]·gw[n] + gb[n]) ----------------
__global__ void gate_kernel(const float* __restrict__ x, const float* __restrict__ gw,
                            const float* __restrict__ gb, float* __restrict__ gT) {
  const int lane = threadIdx.x & 63;
  const int row = blockIdx.x * 4 + (threadIdx.x >> 6);
  const float4* xr = (const float4*)(x + (size_t)row * IDIM);
  float4 xv[4];
#pragma unroll
  for (int t = 0; t < 4; ++t) xv[t] = xr[t * 64 + lane];
  for (int n = 0; n < NEXP; ++n) {
    const float4* wr = (const float4*)(gw + (size_t)n * IDIM);
    float s = 0.f;
#pragma unroll
    for (int t = 0; t < 4; ++t) {
      float4 wv = wr[t * 64 + lane];
      s += xv[t].x * wv.x + xv[t].y * wv.y + xv[t].z * wv.z + xv[t].w * wv.w;
    }
#pragma unroll
    for (int off = 32; off > 0; off >>= 1) s += __shfl_down(s, off, 64);
    if (lane == 0) {
      float v = s + gb[n];
      gT[(size_t)n * BSZ + row] = 0.5f * v * (1.0f + erff(v * 0.70710678118f));
    }
  }
}

// ---------------- main GEMM ----------------
// grid (8, 32, 4): x = N-tile (128), y = M-tile (128), z = split-K (8 experts each)
// 4 waves (2x2), each wave 64x64 = 4x4 fragments of 16x16x32 bf16 MFMA.
__global__ __launch_bounds__(256, 2) void gemm_kernel(
    const unsigned short* __restrict__ xb,   // [4096][1024] bf16
    const unsigned short* __restrict__ wb,   // [32][1024][1024] bf16 (n,o,i)
    const float* __restrict__ gT,            // [32][4096]
    float* __restrict__ out)                 // [4096][1024] fp32
{
  __shared__ unsigned short As[128 * 64];
  __shared__ unsigned short Bs[128 * 64];

  const int tid  = threadIdx.x;
  const int lane = tid & 63;
  const int wid  = tid >> 6;
  const int wm   = wid >> 1, wn = wid & 1;
  const int row0 = blockIdx.y * 128;
  const int col0 = blockIdx.x * 128;
  const int sp   = blockIdx.z;

  const int srow = lane >> 3;        // staging: row within 8-row chunk
  const int scol = (lane & 7) * 8;   // staging: col (elements)

  const int frow = lane & 15;        // fragment A/B row within 16
  const int fcol = (lane >> 4) * 8;  // fragment k-offset

  f32x4 acc[4][4], acc_e[4][4];
#pragma unroll
  for (int i = 0; i < 4; ++i)
#pragma unroll
    for (int j = 0; j < 4; ++j) {
      acc[i][j]   = f32x4{0.f, 0.f, 0.f, 0.f};
      acc_e[i][j] = f32x4{0.f, 0.f, 0.f, 0.f};
    }

  for (int e = 0; e < 8; ++e) {
    const int n = sp * 8 + e;
    const unsigned short* wbase = wb + ((size_t)n << 20);

    for (int kb = 0; kb < 16; ++kb) {
      const int i0 = kb * 64;
      // stage A and B tiles: each wave stages 4 chunks of 1KB per tile
#pragma unroll
      for (int c4 = 0; c4 < 4; ++c4) {
        const int c = wid * 4 + c4;
        const unsigned short* ga = xb + (size_t)(row0 + c * 8 + srow) * IDIM + (i0 + scol);
        GLOAD_LDS16(ga, &As[c * 512]);
        const unsigned short* gw_ = wbase + (size_t)(col0 + c * 8 + srow) * IDIM + (i0 + scol);
        GLOAD_LDS16(gw_, &Bs[c * 512]);
      }
      __syncthreads();

      bf16x8 af[4][2], bfr[4][2];
#pragma unroll
      for (int mi = 0; mi < 4; ++mi)
#pragma unroll
        for (int kk = 0; kk < 2; ++kk) {
          const int r = wm * 64 + mi * 16 + frow;
          af[mi][kk] = *(const bf16x8*)&As[r * 64 + kk * 32 + fcol];
        }
#pragma unroll
      for (int ni = 0; ni < 4; ++ni)
#pragma unroll
        for (int kk = 0; kk < 2; ++kk) {
          const int r = wn * 64 + ni * 16 + frow;
          bfr[ni][kk] = *(const bf16x8*)&Bs[r * 64 + kk * 32 + fcol];
        }
#pragma unroll
      for (int mi = 0; mi < 4; ++mi)
#pragma unroll
        for (int ni = 0; ni < 4; ++ni)
#pragma unroll
          for (int kk = 0; kk < 2; ++kk)
            acc_e[mi][ni] = __builtin_amdgcn_mfma_f32_16x16x32_bf16(
                af[mi][kk], bfr[ni][kk], acc_e[mi][ni], 0, 0, 0);
      __syncthreads();
    }

    // fold expert partial into main accumulator, scaled by g[row, n]
    const float* gp = gT + (size_t)n * BSZ + row0 + wm * 64 + (lane >> 4) * 4;
#pragma unroll
    for (int mi = 0; mi < 4; ++mi) {
      float4 gv = *(const float4*)(gp + mi * 16);
      f32x4 g4 = f32x4{gv.x, gv.y, gv.z, gv.w};
#pragma unroll
      for (int ni = 0; ni < 4; ++ni) {
        acc[mi][ni] += g4 * acc_e[mi][ni];
        acc_e[mi][ni] = f32x4{0.f, 0.f, 0.f, 0.f};
      }
    }
  }

  // atomically add the split's contribution
  const int orow0 = row0 + wm * 64 + (lane >> 4) * 4;
  const int ocol0 = col0 + wn * 64 + (lane & 15);
#pragma unroll
  for (int mi = 0; mi < 4; ++mi)
#pragma unroll
    for (int j = 0; j < 4; ++j) {
      const int r = orow0 + mi * 16 + j;
#pragma unroll
      for (int ni = 0; ni < 4; ++ni)
        atomicAdd(out + (size_t)r * ODIM + ocol0 + ni * 16, acc[mi][ni][j]);
    }
}

extern "C" void kernel_launch(void* const* d_in, const int* in_sizes, int n_in,
                              void* d_out, int out_size, void* d_ws, size_t ws_size,
                              hipStream_t stream) {
  const float* x  = (const float*)d_in[0];   // [4096][1024]
  const float* w  = (const float*)d_in[1];   // [32][1024][1024]
  const float* gw = (const float*)d_in[2];   // [32][1024]
  const float* gb = (const float*)d_in[3];   // [32]
  float* out = (float*)d_out;                // [4096][1024]

  unsigned short* xb   = (unsigned short*)d_ws;                          // 8 MB
  unsigned short* wbuf = (unsigned short*)((char*)d_ws + (8u << 20));    // 64 MB
  float*          gT   = (float*)((char*)d_ws + (72u << 20));            // 512 KB

  // zero the output (atomic accumulation target)
  zero_kernel<<<(BSZ * ODIM / 4) / 256, 256, 0, stream>>>(out);
  // convert x and weight to bf16
  conv_kernel<<<(BSZ * IDIM / 8) / 256, 256, 0, stream>>>(x, xb);
  conv_kernel<<<(NEXP * ODIM * IDIM / 8) / 256, 256, 0, stream>>>(w, wbuf);
  // gate values gT[n][b]
  gate_kernel<<<BSZ / 4, 256, 0, stream>>>(x, gw, gb, gT);
  // main GEMM with per-expert fold + split-K atomics
  dim3 grid(ODIM / 128, BSZ / 128, 4);
  gemm_kernel<<<grid, 256, 0, stream>>>(xb, wbuf, gT, out);
}

// Round 2
// 373.016 us; speedup vs baseline: 1.2974x; 1.2974x over previous
//
#include <hip/hip_runtime.h>
#include <hip/hip_bf16.h>
#include <math.h>

// MOE: out[b,o] = sum_n gelu(x@gw^T+gb)[b,n] * (x @ W_n^T)[b,o]
// B=4096, N=32, IDIM=ODIM=1024.
// bf16 MFMA GEMM (M=4096, N=1024, K=32*1024), per-expert fold by g[b,n],
// split-K x4 via fp32 atomicAdd. R2: double-buffered LDS prefetch (T3-min),
// both-sides LDS XOR swizzle (T2), XCD-chunked group-major block swizzle (T1).

#define BSZ  4096
#define NEXP 32
#define IDIM 1024
#define ODIM 1024

typedef __attribute__((ext_vector_type(8))) short bf16x8;
typedef __attribute__((ext_vector_type(4))) float f32x4;

#define GLOAD_LDS16(g, l) __builtin_amdgcn_global_load_lds( \
    (const __attribute__((address_space(1))) void*)(g),     \
    (__attribute__((address_space(3))) void*)(l), 16, 0, 0)

__device__ __forceinline__ unsigned short f2bf(float f) {
  unsigned u = __float_as_uint(f);
  unsigned r = (u + 0x7FFFu + ((u >> 16) & 1u)) >> 16;  // RNE
  return (unsigned short)r;
}

// ---------------- zero d_out ----------------
__global__ void zero_kernel(float* __restrict__ out) {
  int i = blockIdx.x * blockDim.x + threadIdx.x;  // one float4 each
  ((float4*)out)[i] = make_float4(0.f, 0.f, 0.f, 0.f);
}

// ---------------- fp32 -> bf16 conversion (8 elems/thread) ----------------
__global__ void conv_kernel(const float* __restrict__ in, unsigned short* __restrict__ outb) {
  int i = blockIdx.x * blockDim.x + threadIdx.x;
  const float4* p = (const float4*)in + (size_t)i * 2;
  float4 a = p[0], b = p[1];
  union { bf16x8 v; unsigned short s[8]; } o;
  o.s[0] = f2bf(a.x); o.s[1] = f2bf(a.y); o.s[2] = f2bf(a.z); o.s[3] = f2bf(a.w);
  o.s[4] = f2bf(b.x); o.s[5] = f2bf(b.y); o.s[6] = f2bf(b.z); o.s[7] = f2bf(b.w);
  ((bf16x8*)outb)[i] = o.v;
}

// ---------------- gate: gT[n][b] = gelu(x[b]·gw[n] + gb[n]) ----------------
__global__ void gate_kernel(const float* __restrict__ x, const float* __restrict__ gw,
                            const float* __restrict__ gb, float* __restrict__ gT) {
  const int lane = threadIdx.x & 63;
  const int row = blockIdx.x * 4 + (threadIdx.x >> 6);
  const float4* xr = (const float4*)(x + (size_t)row * IDIM);
  float4 xv[4];
#pragma unroll
  for (int t = 0; t < 4; ++t) xv[t] = xr[t * 64 + lane];
  for (int n = 0; n < NEXP; ++n) {
    const float4* wr = (const float4*)(gw + (size_t)n * IDIM);
    float s = 0.f;
#pragma unroll
    for (int t = 0; t < 4; ++t) {
      float4 wv = wr[t * 64 + lane];
      s += xv[t].x * wv.x + xv[t].y * wv.y + xv[t].z * wv.z + xv[t].w * wv.w;
    }
#pragma unroll
    for (int off = 32; off > 0; off >>= 1) s += __shfl_down(s, off, 64);
    if (lane == 0) {
      float v = s + gb[n];
      gT[(size_t)n * BSZ + row] = 0.5f * v * (1.0f + erff(v * 0.70710678118f));
    }
  }
}

// ---------------- main GEMM ----------------
// 1024 blocks 1-D. wgid = XCD-chunked swizzle; group = (col0,split) with
// mtile innermost so each XCD's resident blocks share a 2MB L2-fit B panel.
// 4 waves (2x2), wave = 64x64 = 4x4 frags of 16x16x32 bf16 MFMA.
// LDS: double-buffered A/B tiles, both-sides XOR swizzle (granule ^= row&7).
__global__ __launch_bounds__(256, 2) void gemm_kernel(
    const unsigned short* __restrict__ xb,   // [4096][1024] bf16
    const unsigned short* __restrict__ wb,   // [32][1024][1024] bf16 (n,o,i)
    const float* __restrict__ gT,            // [32][4096]
    float* __restrict__ out)                 // [4096][1024] fp32
{
  __shared__ unsigned short As[2][128 * 64];
  __shared__ unsigned short Bs[2][128 * 64];

  const int tid  = threadIdx.x;
  const int lane = tid & 63;
  const int wid  = tid >> 6;
  const int wm   = wid >> 1, wn = wid & 1;

  // XCD-chunked, group-major block swizzle (1024 % 8 == 0 -> bijective)
  const int orig  = blockIdx.x;
  const int wgid  = (orig & 7) * 128 + (orig >> 3);
  const int mtile = wgid & 31;            // innermost: same-XCD blocks share B
  const int group = wgid >> 5;            // 0..31 = (col-tile, split)
  const int split = group & 3;
  const int col0  = (group >> 2) * 128;
  const int row0  = mtile * 128;

  // staging: lane -> (row-in-chunk, swizzled source granule)
  const int srow = lane >> 3;
  const int jsrc = (lane & 7) ^ srow;     // pre-swizzled global granule
  size_t a_off[4], b_off[4];
#pragma unroll
  for (int c4 = 0; c4 < 4; ++c4) {
    const int c = wid * 4 + c4;
    a_off[c4] = (size_t)(row0 + c * 8 + srow) * IDIM + jsrc * 8;
    b_off[c4] = (size_t)(col0 + c * 8 + srow) * IDIM + jsrc * 8;
  }

  const int frow = lane & 15;
  const int hi   = lane >> 4;

  f32x4 acc[4][4], acc_e[4][4];
#pragma unroll
  for (int i = 0; i < 4; ++i)
#pragma unroll
    for (int j = 0; j < 4; ++j) {
      acc[i][j]   = f32x4{0.f, 0.f, 0.f, 0.f};
      acc_e[i][j] = f32x4{0.f, 0.f, 0.f, 0.f};
    }

  auto STAGE = [&](int buf, int kt) {
    const int n  = kt >> 4;
    const int i0 = (kt & 15) << 6;
    const unsigned short* wb_n = wb + ((size_t)(split * 8 + n) << 20);
#pragma unroll
    for (int c4 = 0; c4 < 4; ++c4) {
      GLOAD_LDS16(xb + a_off[c4] + i0,   &As[buf][(wid * 4 + c4) * 512]);
      GLOAD_LDS16(wb_n + b_off[c4] + i0, &Bs[buf][(wid * 4 + c4) * 512]);
    }
  };

  STAGE(0, 0);
  __syncthreads();   // drains vmcnt(0) too

  int cur = 0;
  for (int kt = 0; kt < 128; ++kt) {
    if (kt < 127) STAGE(cur ^ 1, kt + 1);   // prefetch next tile

    // fragment loads (swizzled read: granule ^= row&7)
    bf16x8 af[4][2], bfr[4][2];
#pragma unroll
    for (int mi = 0; mi < 4; ++mi)
#pragma unroll
      for (int kk = 0; kk < 2; ++kk) {
        const int r = wm * 64 + mi * 16 + frow;
        const int g = ((kk << 2) + hi) ^ (frow & 7);
        af[mi][kk] = *(const bf16x8*)&As[cur][r * 64 + g * 8];
      }
#pragma unroll
    for (int ni = 0; ni < 4; ++ni)
#pragma unroll
      for (int kk = 0; kk < 2; ++kk) {
        const int r = wn * 64 + ni * 16 + frow;
        const int g = ((kk << 2) + hi) ^ (frow & 7);
        bfr[ni][kk] = *(const bf16x8*)&Bs[cur][r * 64 + g * 8];
      }
#pragma unroll
    for (int mi = 0; mi < 4; ++mi)
#pragma unroll
      for (int ni = 0; ni < 4; ++ni)
#pragma unroll
        for (int kk = 0; kk < 2; ++kk)
          acc_e[mi][ni] = __builtin_amdgcn_mfma_f32_16x16x32_bf16(
              af[mi][kk], bfr[ni][kk], acc_e[mi][ni], 0, 0, 0);

    if ((kt & 15) == 15) {
      // fold expert partial into main accumulator, scaled by g[row, n]
      const int n = kt >> 4;
      const float* gp = gT + ((size_t)(split * 8 + n) << 12) + row0 + wm * 64 + hi * 4;
#pragma unroll
      for (int mi = 0; mi < 4; ++mi) {
        float4 gv = *(const float4*)(gp + mi * 16);
        f32x4 g4 = f32x4{gv.x, gv.y, gv.z, gv.w};
#pragma unroll
        for (int ni = 0; ni < 4; ++ni) {
          acc[mi][ni] += g4 * acc_e[mi][ni];
          acc_e[mi][ni] = f32x4{0.f, 0.f, 0.f, 0.f};
        }
      }
    }

    __syncthreads();   // vmcnt(0)+lgkmcnt(0) drain: next buffer ready
    cur ^= 1;
  }

  // atomically add the split's contribution
  const int orow0 = row0 + wm * 64 + hi * 4;
  const int ocol0 = col0 + wn * 64 + frow;
#pragma unroll
  for (int mi = 0; mi < 4; ++mi)
#pragma unroll
    for (int j = 0; j < 4; ++j) {
      const int r = orow0 + mi * 16 + j;
#pragma unroll
      for (int ni = 0; ni < 4; ++ni)
        atomicAdd(out + (size_t)r * ODIM + ocol0 + ni * 16, acc[mi][ni][j]);
    }
}

extern "C" void kernel_launch(void* const* d_in, const int* in_sizes, int n_in,
                              void* d_out, int out_size, void* d_ws, size_t ws_size,
                              hipStream_t stream) {
  const float* x  = (const float*)d_in[0];   // [4096][1024]
  const float* w  = (const float*)d_in[1];   // [32][1024][1024]
  const float* gw = (const float*)d_in[2];   // [32][1024]
  const float* gb = (const float*)d_in[3];   // [32]
  float* out = (float*)d_out;                // [4096][1024]

  unsigned short* xb   = (unsigned short*)d_ws;                          // 8 MB
  unsigned short* wbuf = (unsigned short*)((char*)d_ws + (8u << 20));    // 64 MB
  float*          gT   = (float*)((char*)d_ws + (72u << 20));            // 512 KB

  zero_kernel<<<(BSZ * ODIM / 4) / 256, 256, 0, stream>>>(out);
  conv_kernel<<<(BSZ * IDIM / 8) / 256, 256, 0, stream>>>(x, xb);
  conv_kernel<<<(NEXP * ODIM * IDIM / 8) / 256, 256, 0, stream>>>(w, wbuf);
  gate_kernel<<<BSZ / 4, 256, 0, stream>>>(x, gw, gb, gT);

  gemm_kernel<<<1024, 256, 0, stream>>>(xb, wbuf, gT, out);
}